// Round 1
// baseline (22192.053 us; speedup 1.0000x reference)
//
#include <hip/hip_runtime.h>
#include <cstddef>

// Problem: 2-layer LSTM decoder, teacher forcing.
// B=2048, Z=64, H=256, D=8, T=250, L=2. All fp32.
//
// Key structural fact: the recurrence is independent per batch row.
// -> 256 workgroups x 8 batch rows each, entire 250-step loop in ONE kernel.
//    No grid sync. h-state in LDS (broadcast reads), c-state in registers,
//    weights (3MB fp32) streamed from L2 every step (L2-resident, shared by
//    all 32 CUs of each XCD).
//
// Thread t (0..255) owns h-index j=t: its gate columns are t, t+256, t+512,
// t+768 (PyTorch i,f,g,o order) -> weight loads are lane-consecutive
// (perfectly coalesced) and the cell update c/h is thread-local.

#define BSZ    2048
#define ZDIM   64
#define HDIM   256
#define DDIM   8
#define TSTEPS 250
#define ROWS   8      // batch rows per workgroup
#define G4     1024   // 4*H

__device__ __forceinline__ float fexp2(float x) { return __builtin_amdgcn_exp2f(x); }
__device__ __forceinline__ float frcp(float x)  { return __builtin_amdgcn_rcpf(x); }
// sigmoid(x) = 1/(1+exp(-x)); tanh(x) = 2*sigmoid(2x)-1. v_exp/v_rcp rel err
// ~1e-6, far below the 8.8e-3 absmax threshold. Saturation: exp2->inf,
// rcp(inf)=0 -> correct +-1 limits.
__device__ __forceinline__ float sigm(float x)  { return frcp(1.f + fexp2(-1.44269504f * x)); }
__device__ __forceinline__ float tanh_(float x) { return 2.f * frcp(1.f + fexp2(-2.88539008f * x)) - 1.f; }

// Initial state: reference does (z @ Wfc + b).reshape(L, B, H) which maps
//   h[l][b][j] = M[l*1024 + b/2, (b&1)*256 + j],  M = z @ W + b  ([2048,512])
__global__ void init_state(const float* __restrict__ z,
                           const float* __restrict__ Wfh, const float* __restrict__ bfh,
                           const float* __restrict__ Wfc, const float* __restrict__ bfc,
                           float* __restrict__ h0s, float* __restrict__ c0s,
                           float* __restrict__ h1s, float* __restrict__ c1s)
{
  int idx = blockIdx.x * 256 + threadIdx.x;   // idx = b*256 + j, 2048*256 total
  int b = idx >> 8;
  int j = idx & 255;
  int col = ((b & 1) << 8) | j;
  const float* z0 = z + (size_t)(b >> 1) * ZDIM;           // layer 0 source row
  const float* z1 = z + (size_t)(1024 + (b >> 1)) * ZDIM;  // layer 1 source row
  float h0 = bfh[col], c0v = bfc[col], h1 = bfh[col], c1v = bfc[col];
  for (int k = 0; k < ZDIM; ++k) {
    float wh = Wfh[k * 512 + col];
    float wc = Wfc[k * 512 + col];
    float a = z0[k], bb = z1[k];
    h0  += a * wh;  c0v += a * wc;
    h1  += bb * wh; c1v += bb * wc;
  }
  h0s[idx] = h0; c0s[idx] = c0v; h1s[idx] = h1; c1s[idx] = c1v;
}

__global__ __launch_bounds__(256, 1) void lstm_run(
    const float* __restrict__ target,          // [B,T,D]
    const float* __restrict__ Wih0,            // [8,1024]
    const float* __restrict__ Whh0,            // [256,1024]
    const float* __restrict__ bih0, const float* __restrict__ bhh0,
    const float* __restrict__ Wih1,            // [256,1024]
    const float* __restrict__ Whh1,            // [256,1024]
    const float* __restrict__ bih1, const float* __restrict__ bhh1,
    const float* __restrict__ Wout,            // [256,8]
    const float* __restrict__ bout,            // [8]
    const float* __restrict__ h0s, const float* __restrict__ c0s,
    const float* __restrict__ h1s, const float* __restrict__ c1s,
    float* __restrict__ out)                   // [B,T,D]
{
  __shared__ float h0_lds[ROWS][HDIM];        // 8 KB
  __shared__ float h1_lds[ROWS][HDIM];        // 8 KB
  __shared__ float wih0_lds[DDIM * G4];       // 32 KB (x-path weights, reused 250x)
  __shared__ float wout_lds[HDIM * DDIM];     // 8 KB
  __shared__ float x_lds[ROWS][DDIM];
  __shared__ float pout[ROWS][DDIM][4];       // out-proj partials

  const int tid = threadIdx.x;   // == owned h-index j
  const int b0  = blockIdx.x * ROWS;

  for (int i = tid; i < DDIM * G4; i += 256) wih0_lds[i] = Wih0[i];
  for (int i = tid; i < HDIM * DDIM; i += 256) wout_lds[i] = Wout[i];

  float c0r[ROWS], c1r[ROWS];
#pragma unroll
  for (int r = 0; r < ROWS; ++r) {
    size_t g = (size_t)(b0 + r) * HDIM + tid;
    h0_lds[r][tid] = h0s[g];
    h1_lds[r][tid] = h1s[g];
    c0r[r] = c0s[g];
    c1r[r] = c1s[g];
  }
  // fold bih+bhh once
  const float bi0 = bih0[tid] + bhh0[tid];
  const float bf0 = bih0[HDIM + tid] + bhh0[HDIM + tid];
  const float bg0 = bih0[2 * HDIM + tid] + bhh0[2 * HDIM + tid];
  const float bo0 = bih0[3 * HDIM + tid] + bhh0[3 * HDIM + tid];
  const float bi1 = bih1[tid] + bhh1[tid];
  const float bf1 = bih1[HDIM + tid] + bhh1[HDIM + tid];
  const float bg1 = bih1[2 * HDIM + tid] + bhh1[2 * HDIM + tid];
  const float bo1 = bih1[3 * HDIM + tid] + bhh1[3 * HDIM + tid];

  // output-projection mapping: thread t = r*32 + d*4 + q computes the partial
  // over k = {q, q+4, q+8, ...} (phase interleave keeps LDS banks spread)
  const int opr = tid >> 5;
  const int opd = (tid >> 2) & 7;
  const int opq = tid & 3;
  const float bo_out = bout[tid & 7];

  __syncthreads();

#pragma unroll 1
  for (int t = 0; t < TSTEPS; ++t) {
    // ---- teacher-forced input: x_t = target[:, t-1], zeros at t=0 ----
    if (tid < ROWS * DDIM) {
      int r = tid >> 3, d = tid & 7;
      x_lds[r][d] = (t == 0) ? 0.f
          : target[(size_t)(b0 + r) * (TSTEPS * DDIM) + (size_t)(t - 1) * DDIM + d];
    }
    __syncthreads();

    // ---- layer 0 gates: x @ Wih0 + h0 @ Whh0 + b ----
    float gi[ROWS], gf[ROWS], gg[ROWS], go[ROWS];
#pragma unroll
    for (int r = 0; r < ROWS; ++r) { gi[r] = bi0; gf[r] = bf0; gg[r] = bg0; go[r] = bo0; }

#pragma unroll
    for (int d = 0; d < DDIM; ++d) {
      float wi = wih0_lds[d * G4 + tid];
      float wf = wih0_lds[d * G4 + HDIM + tid];
      float wg = wih0_lds[d * G4 + 2 * HDIM + tid];
      float wo = wih0_lds[d * G4 + 3 * HDIM + tid];
#pragma unroll
      for (int r = 0; r < ROWS; ++r) {
        float xv = x_lds[r][d];
        gi[r] += xv * wi; gf[r] += xv * wf; gg[r] += xv * wg; go[r] += xv * wo;
      }
    }

#pragma unroll 2
    for (int k = 0; k < HDIM; k += 4) {
      float hv[ROWS][4];
#pragma unroll
      for (int r = 0; r < ROWS; ++r) {        // b128 broadcast reads
        float4 v = *(const float4*)&h0_lds[r][k];
        hv[r][0] = v.x; hv[r][1] = v.y; hv[r][2] = v.z; hv[r][3] = v.w;
      }
#pragma unroll
      for (int kk = 0; kk < 4; ++kk) {
        const float* wp = Whh0 + (size_t)(k + kk) * G4;
        float wi = wp[tid], wf = wp[HDIM + tid], wg = wp[2 * HDIM + tid], wo = wp[3 * HDIM + tid];
#pragma unroll
        for (int r = 0; r < ROWS; ++r) {
          gi[r] += hv[r][kk] * wi; gf[r] += hv[r][kk] * wf;
          gg[r] += hv[r][kk] * wg; go[r] += hv[r][kk] * wo;
        }
      }
    }

    // ---- layer 0 cell update (thread-local: thread t owns h index t) ----
    float hn[ROWS];
#pragma unroll
    for (int r = 0; r < ROWS; ++r) {
      float iv = sigm(gi[r]), fv = sigm(gf[r]), gv = tanh_(gg[r]), ov = sigm(go[r]);
      c0r[r] = fv * c0r[r] + iv * gv;
      hn[r] = ov * tanh_(c0r[r]);
    }
    __syncthreads();                           // all h0_lds reads done
#pragma unroll
    for (int r = 0; r < ROWS; ++r) h0_lds[r][tid] = hn[r];
    __syncthreads();

    // ---- layer 1 gates: h0_new @ Wih1 + h1 @ Whh1 + b ----
#pragma unroll
    for (int r = 0; r < ROWS; ++r) { gi[r] = bi1; gf[r] = bf1; gg[r] = bg1; go[r] = bo1; }
#pragma unroll 2
    for (int k = 0; k < HDIM; k += 4) {
      float av[ROWS][4], bv[ROWS][4];
#pragma unroll
      for (int r = 0; r < ROWS; ++r) {
        float4 v = *(const float4*)&h0_lds[r][k];
        av[r][0] = v.x; av[r][1] = v.y; av[r][2] = v.z; av[r][3] = v.w;
        float4 u = *(const float4*)&h1_lds[r][k];
        bv[r][0] = u.x; bv[r][1] = u.y; bv[r][2] = u.z; bv[r][3] = u.w;
      }
#pragma unroll
      for (int kk = 0; kk < 4; ++kk) {
        const float* wp = Wih1 + (size_t)(k + kk) * G4;
        const float* vp = Whh1 + (size_t)(k + kk) * G4;
        float wi = wp[tid], wf = wp[HDIM + tid], wg = wp[2 * HDIM + tid], wo = wp[3 * HDIM + tid];
        float vi = vp[tid], vf = vp[HDIM + tid], vg = vp[2 * HDIM + tid], vo = vp[3 * HDIM + tid];
#pragma unroll
        for (int r = 0; r < ROWS; ++r) {
          gi[r] += av[r][kk] * wi + bv[r][kk] * vi;
          gf[r] += av[r][kk] * wf + bv[r][kk] * vf;
          gg[r] += av[r][kk] * wg + bv[r][kk] * vg;
          go[r] += av[r][kk] * wo + bv[r][kk] * vo;
        }
      }
    }

    // ---- layer 1 cell update ----
#pragma unroll
    for (int r = 0; r < ROWS; ++r) {
      float iv = sigm(gi[r]), fv = sigm(gf[r]), gv = tanh_(gg[r]), ov = sigm(go[r]);
      c1r[r] = fv * c1r[r] + iv * gv;
      hn[r] = ov * tanh_(c1r[r]);
    }
    __syncthreads();                           // all h0/h1_lds reads done
#pragma unroll
    for (int r = 0; r < ROWS; ++r) h1_lds[r][tid] = hn[r];
    __syncthreads();

    // ---- output projection: out[b,t,:] = h1 @ Wout + bout ----
    {
      float acc = 0.f;
#pragma unroll 8
      for (int i = 0; i < HDIM / 4; ++i) {
        int k = i * 4 + opq;
        acc += h1_lds[opr][k] * wout_lds[k * DDIM + opd];
      }
      pout[opr][opd][opq] = acc;
    }
    __syncthreads();
    if (tid < ROWS * DDIM) {
      int r = tid >> 3, d = tid & 7;
      float v = pout[r][d][0] + pout[r][d][1] + pout[r][d][2] + pout[r][d][3] + bo_out;
      out[(size_t)(b0 + r) * (TSTEPS * DDIM) + (size_t)t * DDIM + d] = v;
    }
    // next iteration's x_lds/pout writes are separated from this iteration's
    // readers by the barriers above
  }
}

extern "C" void kernel_launch(void* const* d_in, const int* in_sizes, int n_in,
                              void* d_out, int out_size, void* d_ws, size_t ws_size,
                              hipStream_t stream) {
  const float* z    = (const float*)d_in[0];
  const float* tgt  = (const float*)d_in[1];
  const float* Wfh  = (const float*)d_in[2];
  const float* bfh  = (const float*)d_in[3];
  const float* Wfc  = (const float*)d_in[4];
  const float* bfc  = (const float*)d_in[5];
  const float* Wih0 = (const float*)d_in[6];
  const float* Whh0 = (const float*)d_in[7];
  const float* bih0 = (const float*)d_in[8];
  const float* bhh0 = (const float*)d_in[9];
  const float* Wih1 = (const float*)d_in[10];
  const float* Whh1 = (const float*)d_in[11];
  const float* bih1 = (const float*)d_in[12];
  const float* bhh1 = (const float*)d_in[13];
  const float* Wout = (const float*)d_in[14];
  const float* bout = (const float*)d_in[15];

  float* ws  = (float*)d_ws;                  // 4 x [2048,256] fp32 = 8 MB
  float* h0s = ws;
  float* c0s = ws + (size_t)BSZ * HDIM;
  float* h1s = ws + 2 * (size_t)BSZ * HDIM;
  float* c1s = ws + 3 * (size_t)BSZ * HDIM;

  hipLaunchKernelGGL(init_state, dim3(BSZ * HDIM / 256), dim3(256), 0, stream,
                     z, Wfh, bfh, Wfc, bfc, h0s, c0s, h1s, c1s);
  hipLaunchKernelGGL(lstm_run, dim3(BSZ / ROWS), dim3(256), 0, stream,
                     tgt, Wih0, Whh0, bih0, bhh0, Wih1, Whh1, bih1, bhh1,
                     Wout, bout, h0s, c0s, h1s, c1s, (float*)d_out);
}

// Round 2
// 6457.679 us; speedup vs baseline: 3.4365x; 3.4365x over previous
//
#include <hip/hip_runtime.h>
#include <cstddef>

// 2-layer LSTM decoder, B=2048, Z=64, H=256, D=8, T=250. fp32 in/out.
//
// R2: bf16 MFMA formulation.
//  - Per WG: 16 batch rows, full 250-step loop, no grid sync (rows independent).
//  - gates = X @ W via mfma_f32_16x16x32_bf16, fp32 accumulators.
//    A (X) lives in LDS row-major bf16; B (W) pre-packed one-time into exact
//    fragment lane order -> each MFMA's B-load is ONE coalesced dwordx4 (1KB/wave).
//  - c-state, biases, activations, out-proj all fp32. h rounded to bf16 only
//    as matmul operand.
//  - Wave w owns h-slice j in [32w,32w+32): N-tiles {g*16+2w, g*16+2w+1} for
//    gate g -> i,f,g,o land in the same thread (C-layout col=lane&15,
//    row=(lane>>4)*4+reg) -> thread-local cell update, c-state in registers.
//  - Expected regime: L2->CU weight stream bound (1.6 MB bf16/CU/step).

#define BSZ    2048
#define ZDIM   64
#define HDIM   256
#define DDIM   8
#define TSTEPS 250
#define ROWS   16
#define NWG    (BSZ / ROWS)   // 128
#define NTH    512            // 8 waves
#define G4     1024

typedef __attribute__((ext_vector_type(8))) short short8;   // 8 bf16 = 4 VGPR
typedef __attribute__((ext_vector_type(4))) float f32x4;

__device__ __forceinline__ unsigned short f2bf(float x) {   // RNE f32->bf16
  union { float f; unsigned u; } v; v.f = x;
  unsigned r = v.u + 0x7fff + ((v.u >> 16) & 1);
  return (unsigned short)(r >> 16);
}
__device__ __forceinline__ float fexp2(float x) { return __builtin_amdgcn_exp2f(x); }
__device__ __forceinline__ float frcp(float x)  { return __builtin_amdgcn_rcpf(x); }
__device__ __forceinline__ float sigm(float x)  { return frcp(1.f + fexp2(-1.44269504f * x)); }
__device__ __forceinline__ float tanh_(float x) { return 2.f * frcp(1.f + fexp2(-2.88539008f * x)) - 1.f; }

// ---------------- initial state (verified mapping from R1) ----------------
// h[l][b][j] = M[l*1024 + b/2, (b&1)*256 + j], M = z @ Wfc/Wfh + b
__global__ void init_state(const float* __restrict__ z,
                           const float* __restrict__ Wfh, const float* __restrict__ bfh,
                           const float* __restrict__ Wfc, const float* __restrict__ bfc,
                           unsigned short* __restrict__ h0b, float* __restrict__ c0s,
                           unsigned short* __restrict__ h1b, float* __restrict__ c1s)
{
  int idx = blockIdx.x * 256 + threadIdx.x;   // b*256 + j
  int b = idx >> 8;
  int j = idx & 255;
  int col = ((b & 1) << 8) | j;
  const float* z0 = z + (size_t)(b >> 1) * ZDIM;
  const float* z1 = z + (size_t)(1024 + (b >> 1)) * ZDIM;
  float h0 = bfh[col], c0v = bfc[col], h1 = bfh[col], c1v = bfc[col];
  for (int k = 0; k < ZDIM; ++k) {
    float wh = Wfh[k * 512 + col];
    float wc = Wfc[k * 512 + col];
    float a = z0[k], bb = z1[k];
    h0  += a * wh;  c0v += a * wc;
    h1  += bb * wh; c1v += bb * wc;
  }
  h0b[idx] = f2bf(h0); c0s[idx] = c0v;
  h1b[idx] = f2bf(h1); c1s[idx] = c1v;
}

// ---------------- one-time weight pack into B-fragment order ----------------
// B-frag (16x16x32): lane l holds W[k = kc*32 + (l>>4)*8 + j][n = nt*16 + (l&15)]
// p[(kc*64+nt)*64 + l] = 8 bf16.  Layer0 k-space: 0..255 Whh0, 256..263 Wih0,
// 264..287 zero-pad.  Layer1: 0..255 Wih1 (h0' first in X1), 256..511 Whh1.
__global__ void pack_weights(const float* __restrict__ Wih0, const float* __restrict__ Whh0,
                             const float* __restrict__ Wih1, const float* __restrict__ Whh1,
                             unsigned short* __restrict__ p0, unsigned short* __restrict__ p1)
{
  int tt   = blockIdx.x * 4 + (threadIdx.x >> 6);   // tile id
  int lane = threadIdx.x & 63;
  int l15 = lane & 15, lq = lane >> 4;
  unsigned short vals[8];
  if (tt < 576) {                                   // layer0: 9 kc x 64 nt
    int kc = tt >> 6, nt = tt & 63;
    int col = nt * 16 + l15;
    for (int j = 0; j < 8; ++j) {
      int k = kc * 32 + lq * 8 + j;
      float v = (k < 256) ? Whh0[(size_t)k * G4 + col]
              : (k < 264) ? Wih0[(size_t)(k - 256) * G4 + col] : 0.f;
      vals[j] = f2bf(v);
    }
    *(uint4*)(p0 + ((size_t)tt * 64 + lane) * 8) = *(const uint4*)vals;
  } else {                                          // layer1: 16 kc x 64 nt
    int t1 = tt - 576;
    int kc = t1 >> 6, nt = t1 & 63;
    int col = nt * 16 + l15;
    for (int j = 0; j < 8; ++j) {
      int k = kc * 32 + lq * 8 + j;
      float v = (k < 256) ? Wih1[(size_t)k * G4 + col]
                          : Whh1[(size_t)(k - 256) * G4 + col];
      vals[j] = f2bf(v);
    }
    *(uint4*)(p1 + ((size_t)t1 * 64 + lane) * 8) = *(const uint4*)vals;
  }
}

// ---------------- persistent LSTM kernel ----------------
__global__ __launch_bounds__(NTH, 2) void lstm_run(
    const float* __restrict__ target,
    const unsigned short* __restrict__ p0,
    const unsigned short* __restrict__ p1,
    const float* __restrict__ bih0, const float* __restrict__ bhh0,
    const float* __restrict__ bih1, const float* __restrict__ bhh1,
    const float* __restrict__ Wout, const float* __restrict__ bout,
    const unsigned short* __restrict__ h0b, const unsigned short* __restrict__ h1b,
    const float* __restrict__ c0s, const float* __restrict__ c1s,
    float* __restrict__ out)
{
  // strides padded so row stride % 32 dwords == 4 -> <=2-way LDS aliasing (free)
  __shared__ unsigned short X0[16][296];   // k: 0..255 h0 | 256..263 x | 264..287 zero
  __shared__ unsigned short X1[16][520];   // k: 0..255 h0_new | 256..511 h1
  __shared__ float h1f[16][260];           // fp32 h1 for out-proj
  __shared__ float woutT[8][260];          // Wout transposed
  __shared__ float pout[16][8][4];

  const int tid  = threadIdx.x;
  const int w    = tid >> 6;        // wave 0..7
  const int lane = tid & 63;
  const int l15  = lane & 15;
  const int lq   = lane >> 4;
  const int b0   = blockIdx.x * ROWS;

  // ---- one-time staging ----
  {
    int m = tid >> 5;               // 0..15
    int col = (tid & 31) * 8;
    *(uint4*)&X0[m][col]       = *(const uint4*)(h0b + (size_t)(b0 + m) * HDIM + col);
    *(uint4*)&X1[m][256 + col] = *(const uint4*)(h1b + (size_t)(b0 + m) * HDIM + col);
  }
  if (tid < 384) { int m = tid / 24, c = 264 + tid % 24; X0[m][c] = 0; }
  for (int i = tid; i < HDIM * DDIM; i += NTH) { int k = i >> 3, d = i & 7; woutT[d][k] = Wout[i]; }

  // C-layout state: thread owns rows myrow..myrow+3, cols jc0 and jc0+16
  const int myrow = lq * 4;
  const int jc0   = 32 * w + l15;
  float c0r[2][4], c1r[2][4];
  float bL0[4][2], bL1[4][2];
#pragma unroll
  for (int cc = 0; cc < 2; ++cc) {
    int j = jc0 + cc * 16;
#pragma unroll
    for (int r = 0; r < 4; ++r) {
      c0r[cc][r] = c0s[(size_t)(b0 + myrow + r) * HDIM + j];
      c1r[cc][r] = c1s[(size_t)(b0 + myrow + r) * HDIM + j];
    }
#pragma unroll
    for (int g = 0; g < 4; ++g) {
      bL0[g][cc] = bih0[g * HDIM + j] + bhh0[g * HDIM + j];
      bL1[g][cc] = bih1[g * HDIM + j] + bhh1[g * HDIM + j];
    }
  }
  const int opr = tid >> 5, opd = (tid >> 2) & 7, opq = tid & 3;
  const float bo_out = bout[tid & 7];
  const int nt0 = 2 * w;            // wave's base N-tile inside each gate block
  const short8* bp0 = (const short8*)p0;
  const short8* bp1 = (const short8*)p1;

  __syncthreads();

  for (int t = 0; t < TSTEPS; ++t) {
    // ---- teacher-forced input ----
    if (tid < 128) {
      int m = tid >> 3, d = tid & 7;
      float xv = (t == 0) ? 0.f
               : target[(size_t)(b0 + m) * (TSTEPS * DDIM) + (size_t)(t - 1) * DDIM + d];
      X0[m][256 + d] = f2bf(xv);
    }
    __syncthreads();

    // ---- layer 0: gates0 = X0 @ W0 (K=288) ----
    f32x4 acc[4][2];
    const f32x4 zf = {0.f, 0.f, 0.f, 0.f};
#pragma unroll
    for (int g = 0; g < 4; ++g)
#pragma unroll
      for (int cc = 0; cc < 2; ++cc) acc[g][cc] = zf;
#pragma unroll 3
    for (int kc = 0; kc < 9; ++kc) {
      short8 a = *(const short8*)&X0[l15][kc * 32 + lq * 8];
      size_t base = (size_t)kc * 64 * 64 + lane;
#pragma unroll
      for (int g = 0; g < 4; ++g)
#pragma unroll
        for (int cc = 0; cc < 2; ++cc) {
          short8 b = bp0[base + (size_t)(g * 16 + nt0 + cc) * 64];
          acc[g][cc] = __builtin_amdgcn_mfma_f32_16x16x32_bf16(a, b, acc[g][cc], 0, 0, 0);
        }
    }
    __syncthreads();                 // all X0 reads done

    // ---- cell 0 (thread-local) + publish h0_new as bf16 ----
#pragma unroll
    for (int cc = 0; cc < 2; ++cc) {
      int j = jc0 + cc * 16;
#pragma unroll
      for (int r = 0; r < 4; ++r) {
        float iv = sigm(acc[0][cc][r] + bL0[0][cc]);
        float fv = sigm(acc[1][cc][r] + bL0[1][cc]);
        float gv = tanh_(acc[2][cc][r] + bL0[2][cc]);
        float ov = sigm(acc[3][cc][r] + bL0[3][cc]);
        c0r[cc][r] = fv * c0r[cc][r] + iv * gv;
        unsigned short hb = f2bf(ov * tanh_(c0r[cc][r]));
        X0[myrow + r][j] = hb;       // for next step's layer0
        X1[myrow + r][j] = hb;       // for this step's layer1
      }
    }
    __syncthreads();                 // h0_new visible

    // ---- layer 1: gates1 = X1 @ W1 (K=512) ----
#pragma unroll
    for (int g = 0; g < 4; ++g)
#pragma unroll
      for (int cc = 0; cc < 2; ++cc) acc[g][cc] = zf;
#pragma unroll 4
    for (int kc = 0; kc < 16; ++kc) {
      short8 a = *(const short8*)&X1[l15][kc * 32 + lq * 8];
      size_t base = (size_t)kc * 64 * 64 + lane;
#pragma unroll
      for (int g = 0; g < 4; ++g)
#pragma unroll
        for (int cc = 0; cc < 2; ++cc) {
          short8 b = bp1[base + (size_t)(g * 16 + nt0 + cc) * 64];
          acc[g][cc] = __builtin_amdgcn_mfma_f32_16x16x32_bf16(a, b, acc[g][cc], 0, 0, 0);
        }
    }
    __syncthreads();                 // all X1 reads done

    // ---- cell 1 + publish h1 (bf16 for matmul, fp32 for out-proj) ----
#pragma unroll
    for (int cc = 0; cc < 2; ++cc) {
      int j = jc0 + cc * 16;
#pragma unroll
      for (int r = 0; r < 4; ++r) {
        float iv = sigm(acc[0][cc][r] + bL1[0][cc]);
        float fv = sigm(acc[1][cc][r] + bL1[1][cc]);
        float gv = tanh_(acc[2][cc][r] + bL1[2][cc]);
        float ov = sigm(acc[3][cc][r] + bL1[3][cc]);
        c1r[cc][r] = fv * c1r[cc][r] + iv * gv;
        float h = ov * tanh_(c1r[cc][r]);
        X1[myrow + r][256 + j] = f2bf(h);
        h1f[myrow + r][j] = h;
      }
    }
    __syncthreads();                 // h1_new visible

    // ---- out projection: out[b,t,:] = h1 @ Wout + bout (fp32) ----
    {
      float s = 0.f;
#pragma unroll
      for (int i = 0; i < 16; ++i) {
        int k = opq * 64 + i * 4;
        float4 wv = *(const float4*)&woutT[opd][k];
        float4 hv = *(const float4*)&h1f[opr][k];
        s += hv.x * wv.x + hv.y * wv.y + hv.z * wv.z + hv.w * wv.w;
      }
      pout[opr][opd][opq] = s;
    }
    __syncthreads();
    if (tid < 128) {
      int m = tid >> 3, d = tid & 7;
      float v = pout[m][d][0] + pout[m][d][1] + pout[m][d][2] + pout[m][d][3] + bo_out;
      out[(size_t)(b0 + m) * (TSTEPS * DDIM) + (size_t)t * DDIM + d] = v;
    }
    // next writers (x, pout) are separated from these readers by the barriers
    // at the top of the next phase chain
  }
}

extern "C" void kernel_launch(void* const* d_in, const int* in_sizes, int n_in,
                              void* d_out, int out_size, void* d_ws, size_t ws_size,
                              hipStream_t stream) {
  const float* z    = (const float*)d_in[0];
  const float* tgt  = (const float*)d_in[1];
  const float* Wfh  = (const float*)d_in[2];
  const float* bfh  = (const float*)d_in[3];
  const float* Wfc  = (const float*)d_in[4];
  const float* bfc  = (const float*)d_in[5];
  const float* Wih0 = (const float*)d_in[6];
  const float* Whh0 = (const float*)d_in[7];
  const float* bih0 = (const float*)d_in[8];
  const float* bhh0 = (const float*)d_in[9];
  const float* Wih1 = (const float*)d_in[10];
  const float* Whh1 = (const float*)d_in[11];
  const float* bih1 = (const float*)d_in[12];
  const float* bhh1 = (const float*)d_in[13];
  const float* Wout = (const float*)d_in[14];
  const float* bout = (const float*)d_in[15];

  // ws layout (bytes), total ~7.93 MB (R1 proved >=8 MB available)
  char* ws = (char*)d_ws;
  unsigned short* p0  = (unsigned short*)(ws);                    // 589,824 B
  unsigned short* p1  = (unsigned short*)(ws + 589824);           // 1,048,576 B
  unsigned short* h0b = (unsigned short*)(ws + 1638400);          // 1,048,576 B
  unsigned short* h1b = (unsigned short*)(ws + 2686976);          // 1,048,576 B
  float*          c0s = (float*)(ws + 3735552);                   // 2,097,152 B
  float*          c1s = (float*)(ws + 5832704);                   // 2,097,152 B

  hipLaunchKernelGGL(init_state, dim3(BSZ * HDIM / 256), dim3(256), 0, stream,
                     z, Wfh, bfh, Wfc, bfc, h0b, c0s, h1b, c1s);
  hipLaunchKernelGGL(pack_weights, dim3(400), dim3(256), 0, stream,
                     Wih0, Whh0, Wih1, Whh1, p0, p1);
  hipLaunchKernelGGL(lstm_run, dim3(NWG), dim3(NTH), 0, stream,
                     tgt, p0, p1, bih0, bhh0, bih1, bhh1, Wout, bout,
                     h0b, h1b, c0s, c1s, (float*)d_out);
}

// Round 3
// 4684.709 us; speedup vs baseline: 4.7371x; 1.3785x over previous
//
#include <hip/hip_runtime.h>
#include <cstddef>
#include <cstdint>

// 2-layer LSTM decoder, B=2048, Z=64, H=256, D=8, T=250. fp32 in/out.
//
// R3: weight stream via async global_load_lds (VGPR-free, deep pipeline).
//  - 128 WGs x 16 batch rows, full 250-step loop per WG, no grid sync.
//  - gates via mfma_f32_16x16x32_bf16, fp32 accum; c-state/activations fp32.
//  - Weights pre-packed in per-(kc,wave,tile) order; each wave streams its
//    8 tiles/kc into a private 4-slot x 1KB LDS ring with
//    __builtin_amdgcn_global_load_lds(16B) + manual s_waitcnt vmcnt(3).
//    No VGPR held per load -> ~4KB in flight/wave, 32KB/CU -> should reach
//    the ~60 B/cyc/CU L2-read ceiling (R2 measured only 26 B/cyc).
//  - Per-WG kc rotation de-correlates the identical weight address streams
//    of the 128 CUs (L2 bank pressure hedge). Changes only fp32 summation
//    order.
//  - Single X buffer: cols [0,256)=h1, [256,512)=h0, [512,520)=x, [520,544)=0.
//    Layer1 K-order is [h1 | h0'] (weights packed to match).
//  - LDS 57.3KB static (<=64KB safe limit).

#define BSZ    2048
#define ZDIM   64
#define HDIM   256
#define DDIM   8
#define TSTEPS 250
#define ROWS   16
#define NWG    (BSZ / ROWS)   // 128
#define NTH    512            // 8 waves
#define G4     1024
#define XSTR   568            // X row stride (shorts): 284 dwords = 28 mod 32 -> 2-way (free)

typedef __attribute__((ext_vector_type(8))) short short8;   // 8 bf16 = 4 VGPR
typedef __attribute__((ext_vector_type(4))) float f32x4;

__device__ __forceinline__ unsigned short f2bf(float x) {   // RNE f32->bf16
  union { float f; unsigned u; } v; v.f = x;
  unsigned r = v.u + 0x7fff + ((v.u >> 16) & 1);
  return (unsigned short)(r >> 16);
}
__device__ __forceinline__ float bf2f(unsigned short b) {
  union { unsigned u; float f; } v; v.u = (unsigned)b << 16; return v.f;
}
__device__ __forceinline__ float fexp2(float x) { return __builtin_amdgcn_exp2f(x); }
__device__ __forceinline__ float frcp(float x)  { return __builtin_amdgcn_rcpf(x); }
__device__ __forceinline__ float sigm(float x)  { return frcp(1.f + fexp2(-1.44269504f * x)); }
__device__ __forceinline__ float tanh_(float x) { return 2.f * frcp(1.f + fexp2(-2.88539008f * x)) - 1.f; }

// async 16B/lane global->LDS DMA: lane l's 16B land at ldsbase + l*16
__device__ __forceinline__ void async_copy16(const void* g, void* l) {
  __builtin_amdgcn_global_load_lds(
      reinterpret_cast<const __attribute__((address_space(1))) unsigned int*>(
          reinterpret_cast<uintptr_t>(g)),
      reinterpret_cast<__attribute__((address_space(3))) unsigned int*>(
          reinterpret_cast<uintptr_t>(l)),
      16, 0, 0);
}
// s_waitcnt vmcnt(N) only (exp/lgkm fields = don't-wait)
template <int N>
__device__ __forceinline__ void wait_vmcnt() {
  __builtin_amdgcn_s_waitcnt((N & 15) | (7 << 4) | (15 << 8) | (((N >> 4) & 3) << 14));
}

// ---------------- initial state (verified mapping, R1/R2) ----------------
__global__ void init_state(const float* __restrict__ z,
                           const float* __restrict__ Wfh, const float* __restrict__ bfh,
                           const float* __restrict__ Wfc, const float* __restrict__ bfc,
                           unsigned short* __restrict__ h0b, float* __restrict__ c0s,
                           unsigned short* __restrict__ h1b, float* __restrict__ c1s)
{
  int idx = blockIdx.x * 256 + threadIdx.x;   // b*256 + j
  int b = idx >> 8;
  int j = idx & 255;
  int col = ((b & 1) << 8) | j;
  const float* z0 = z + (size_t)(b >> 1) * ZDIM;
  const float* z1 = z + (size_t)(1024 + (b >> 1)) * ZDIM;
  float h0 = bfh[col], c0v = bfc[col], h1 = bfh[col], c1v = bfc[col];
  for (int k = 0; k < ZDIM; ++k) {
    float wh = Wfh[k * 512 + col];
    float wc = Wfc[k * 512 + col];
    float a = z0[k], bb = z1[k];
    h0  += a * wh;  c0v += a * wc;
    h1  += bb * wh; c1v += bb * wc;
  }
  h0b[idx] = f2bf(h0); c0s[idx] = c0v;
  h1b[idx] = f2bf(h1); c1s[idx] = c1v;
}

// -------- one-time weight pack, streaming order [kc][wave][tile][lane] --------
// tile index i in [0,8): gate g=i>>1, cc=i&1, ntile = g*16 + 2*w + cc.
// B-frag layout per tile: lane l holds W[k = kc*32 + (l>>4)*8 + j][n = ntile*16 + (l&15)]
// Layer0 K-space (288): 0..255 Whh0 | 256..263 Wih0 | pad 0.
// Layer1 K-space (512): 0..255 Whh1 (h1 FIRST) | 256..511 Wih1 (h0').
__global__ void pack_weights(const float* __restrict__ Wih0, const float* __restrict__ Whh0,
                             const float* __restrict__ Wih1, const float* __restrict__ Whh1,
                             unsigned short* __restrict__ p0, unsigned short* __restrict__ p1)
{
  int tt   = blockIdx.x * 4 + (threadIdx.x >> 6);   // global tile id, 1600 total
  int lane = threadIdx.x & 63;
  int l15 = lane & 15, lq = lane >> 4;
  unsigned short vals[8];
  if (tt < 576) {                                   // layer0: 9 kc x 8 w x 8 i
    int kc = tt >> 6, w = (tt >> 3) & 7, i = tt & 7;
    int nt = (i >> 1) * 16 + 2 * w + (i & 1);
    int col = nt * 16 + l15;
    for (int j = 0; j < 8; ++j) {
      int k = kc * 32 + lq * 8 + j;
      float v = (k < 256) ? Whh0[(size_t)k * G4 + col]
              : (k < 264) ? Wih0[(size_t)(k - 256) * G4 + col] : 0.f;
      vals[j] = f2bf(v);
    }
    *(uint4*)(p0 + ((size_t)tt * 64 + lane) * 8) = *(const uint4*)vals;
  } else {                                          // layer1: 16 kc x 8 w x 8 i
    int t1 = tt - 576;
    int kc = t1 >> 6, w = (t1 >> 3) & 7, i = t1 & 7;
    int nt = (i >> 1) * 16 + 2 * w + (i & 1);
    int col = nt * 16 + l15;
    for (int j = 0; j < 8; ++j) {
      int k = kc * 32 + lq * 8 + j;
      float v = (k < 256) ? Whh1[(size_t)k * G4 + col]
                          : Wih1[(size_t)(k - 256) * G4 + col];
      vals[j] = f2bf(v);
    }
    *(uint4*)(p1 + ((size_t)t1 * 64 + lane) * 8) = *(const uint4*)vals;
  }
}

// ---------------- persistent LSTM kernel ----------------
__global__ __launch_bounds__(NTH, 2) void lstm_run(
    const float* __restrict__ target,
    const unsigned short* __restrict__ p0,
    const unsigned short* __restrict__ p1,
    const float* __restrict__ bih0, const float* __restrict__ bhh0,
    const float* __restrict__ bih1, const float* __restrict__ bhh1,
    const float* __restrict__ Wout, const float* __restrict__ bout,
    const unsigned short* __restrict__ h0b, const unsigned short* __restrict__ h1b,
    const float* __restrict__ c0s, const float* __restrict__ c1s,
    float* __restrict__ out)
{
  __shared__ unsigned short wlds[8][4][512];  // per-wave 4-slot x 1KB tile ring (32 KB)
  __shared__ unsigned short X[16][XSTR];      // 18.2 KB (cols: h1|h0|x|pad)
  __shared__ unsigned short woutT[8][272];    // bf16 Wout^T, 4.3 KB
  __shared__ float pout[16][8][4];            // 2 KB

  const int tid  = threadIdx.x;
  const int w    = tid >> 6;        // wave 0..7
  const int lane = tid & 63;
  const int l15  = lane & 15;
  const int lq   = lane >> 4;
  const int b0   = blockIdx.x * ROWS;
  const int rot0 = blockIdx.x % 9;
  const int rot1 = blockIdx.x % 16;

  unsigned short* wl = &wlds[w][0][0];
  const short8* bp0 = (const short8*)p0;
  const short8* bp1 = (const short8*)p1;

  // ---- one-time staging ----
  {
    int m = tid >> 5;               // 0..15
    int col = (tid & 31) * 8;
    *(uint4*)&X[m][col]       = *(const uint4*)(h1b + (size_t)(b0 + m) * HDIM + col);
    *(uint4*)&X[m][256 + col] = *(const uint4*)(h0b + (size_t)(b0 + m) * HDIM + col);
  }
  if (tid < 384) { int m = tid / 24, c = 520 + tid % 24; X[m][c] = 0; }
  for (int i = tid; i < HDIM * DDIM; i += NTH) {
    int k = i >> 3, d = i & 7;
    woutT[d][k] = f2bf(Wout[i]);
  }

  // C-layout state: thread owns rows myrow..+3, gate-cols jc0 and jc0+16
  const int myrow = lq * 4;
  const int jc0   = 32 * w + l15;
  float c0r[2][4], c1r[2][4];
  float bL0[4][2], bL1[4][2];
#pragma unroll
  for (int cc = 0; cc < 2; ++cc) {
    int j = jc0 + cc * 16;
#pragma unroll
    for (int r = 0; r < 4; ++r) {
      c0r[cc][r] = c0s[(size_t)(b0 + myrow + r) * HDIM + j];
      c1r[cc][r] = c1s[(size_t)(b0 + myrow + r) * HDIM + j];
    }
#pragma unroll
    for (int g = 0; g < 4; ++g) {
      bL0[g][cc] = bih0[g * HDIM + j] + bhh0[g * HDIM + j];
      bL1[g][cc] = bih1[g * HDIM + j] + bhh1[g * HDIM + j];
    }
  }
  const int opr = tid >> 5, opd = (tid >> 2) & 7, opq = tid & 3;
  const float bo_out = bout[tid & 7];

  __syncthreads();

  for (int t = 0; t < TSTEPS; ++t) {
    // ---- teacher-forced input ----
    if (tid < 128) {
      int m = tid >> 3, d = tid & 7;
      float xv = (t == 0) ? 0.f
               : target[(size_t)(b0 + m) * (TSTEPS * DDIM) + (size_t)(t - 1) * DDIM + d];
      X[m][512 + d] = f2bf(xv);
    }
    __syncthreads();   // (1) x visible; also drains out-store/x-load vmcnt ->
                       //     manual vmcnt below counts ONLY weight DMAs

    f32x4 acc[4][2];
    const f32x4 zf = {0.f, 0.f, 0.f, 0.f};

    // ================= layer 0: gates0 = [h0|x|0] @ W0, KC=9 =================
#pragma unroll
    for (int g = 0; g < 4; ++g)
#pragma unroll
      for (int cc = 0; cc < 2; ++cc) acc[g][cc] = zf;
    {
#pragma unroll
      for (int kt = 0; kt < 4; ++kt) {          // prologue: fill ring
        int kcr = (kt >> 3) + rot0; if (kcr >= 9) kcr -= 9;
        async_copy16((const void*)(bp0 + ((size_t)(kcr * 8 + w) * 8 + (kt & 7)) * 64 + lane),
                     (void*)(wl + (kt & 3) * 512));
      }
      short8 a;
#pragma unroll 8
      for (int kt = 0; kt < 72; ++kt) {
        const int i = kt & 7, slot = kt & 3;
        if (i == 0) {
          int kcr = (kt >> 3) + rot0; if (kcr >= 9) kcr -= 9;
          a = *(const short8*)&X[l15][256 + kcr * 32 + lq * 8];
        }
        if (kt < 69) wait_vmcnt<3>(); else wait_vmcnt<0>();
        short8 b = *(const short8*)&wl[slot * 512 + lane * 8];
        acc[i >> 1][i & 1] =
            __builtin_amdgcn_mfma_f32_16x16x32_bf16(a, b, acc[i >> 1][i & 1], 0, 0, 0);
        if (kt + 4 < 72) {
          int kn = kt + 4;
          int kcr = (kn >> 3) + rot0; if (kcr >= 9) kcr -= 9;
          async_copy16((const void*)(bp0 + ((size_t)(kcr * 8 + w) * 8 + (kn & 7)) * 64 + lane),
                       (void*)(wl + (kn & 3) * 512));
        }
      }
    }
    __syncthreads();   // (2) all waves' L0 A-reads done

    // ---- cell 0 (thread-local) ----
    unsigned short hnb[2][4];
#pragma unroll
    for (int cc = 0; cc < 2; ++cc)
#pragma unroll
      for (int r = 0; r < 4; ++r) {
        float iv = sigm(acc[0][cc][r] + bL0[0][cc]);
        float fv = sigm(acc[1][cc][r] + bL0[1][cc]);
        float gv = tanh_(acc[2][cc][r] + bL0[2][cc]);
        float ov = sigm(acc[3][cc][r] + bL0[3][cc]);
        c0r[cc][r] = fv * c0r[cc][r] + iv * gv;
        hnb[cc][r] = f2bf(ov * tanh_(c0r[cc][r]));
      }
#pragma unroll
    for (int cc = 0; cc < 2; ++cc)
#pragma unroll
      for (int r = 0; r < 4; ++r)
        X[myrow + r][256 + jc0 + cc * 16] = hnb[cc][r];
    __syncthreads();   // (3) h0' visible

    // ================= layer 1: gates1 = [h1|h0'] @ W1, KC=16 =================
#pragma unroll
    for (int g = 0; g < 4; ++g)
#pragma unroll
      for (int cc = 0; cc < 2; ++cc) acc[g][cc] = zf;
    {
#pragma unroll
      for (int kt = 0; kt < 4; ++kt) {
        int kcr = (kt >> 3) + rot1; if (kcr >= 16) kcr -= 16;
        async_copy16((const void*)(bp1 + ((size_t)(kcr * 8 + w) * 8 + (kt & 7)) * 64 + lane),
                     (void*)(wl + (kt & 3) * 512));
      }
      short8 a;
#pragma unroll 8
      for (int kt = 0; kt < 128; ++kt) {
        const int i = kt & 7, slot = kt & 3;
        if (i == 0) {
          int kcr = (kt >> 3) + rot1; if (kcr >= 16) kcr -= 16;
          a = *(const short8*)&X[l15][kcr * 32 + lq * 8];
        }
        if (kt < 125) wait_vmcnt<3>(); else wait_vmcnt<0>();
        short8 b = *(const short8*)&wl[slot * 512 + lane * 8];
        acc[i >> 1][i & 1] =
            __builtin_amdgcn_mfma_f32_16x16x32_bf16(a, b, acc[i >> 1][i & 1], 0, 0, 0);
        if (kt + 4 < 128) {
          int kn = kt + 4;
          int kcr = (kn >> 3) + rot1; if (kcr >= 16) kcr -= 16;
          async_copy16((const void*)(bp1 + ((size_t)(kcr * 8 + w) * 8 + (kn & 7)) * 64 + lane),
                       (void*)(wl + (kn & 3) * 512));
        }
      }
    }
    __syncthreads();   // (4) all waves' L1 A-reads done

    // ---- cell 1 ----
#pragma unroll
    for (int cc = 0; cc < 2; ++cc)
#pragma unroll
      for (int r = 0; r < 4; ++r) {
        float iv = sigm(acc[0][cc][r] + bL1[0][cc]);
        float fv = sigm(acc[1][cc][r] + bL1[1][cc]);
        float gv = tanh_(acc[2][cc][r] + bL1[2][cc]);
        float ov = sigm(acc[3][cc][r] + bL1[3][cc]);
        c1r[cc][r] = fv * c1r[cc][r] + iv * gv;
        hnb[cc][r] = f2bf(ov * tanh_(c1r[cc][r]));
      }
#pragma unroll
    for (int cc = 0; cc < 2; ++cc)
#pragma unroll
      for (int r = 0; r < 4; ++r)
        X[myrow + r][jc0 + cc * 16] = hnb[cc][r];
    __syncthreads();   // (5) h1 visible

    // ---- out projection: out[b,t,:] = h1 @ Wout + bout ----
    // thread (opr,opd,opq) partial over k = i*16 + opq*4 + 0..3 (bank-spread)
    {
      float s = 0.f;
#pragma unroll
      for (int i = 0; i < 16; ++i) {
        int k = i * 16 + opq * 4;
        ushort4 hx = *(const ushort4*)&X[opr][k];
        ushort4 wx = *(const ushort4*)&woutT[opd][k];
        s += bf2f(hx.x) * bf2f(wx.x) + bf2f(hx.y) * bf2f(wx.y)
           + bf2f(hx.z) * bf2f(wx.z) + bf2f(hx.w) * bf2f(wx.w);
      }
      pout[opr][opd][opq] = s;
    }
    __syncthreads();   // (6) partials visible
    if (tid < 128) {
      int m = tid >> 3, d = tid & 7;
      float v = pout[m][d][0] + pout[m][d][1] + pout[m][d][2] + pout[m][d][3] + bo_out;
      out[(size_t)(b0 + m) * (TSTEPS * DDIM) + (size_t)t * DDIM + d] = v;
    }
    // barrier (1) of the next iteration separates this store / next x-write
    // from all readers, and its implicit vmcnt(0) drain keeps manual vmcnt
    // counting weight DMAs only.
  }
}

extern "C" void kernel_launch(void* const* d_in, const int* in_sizes, int n_in,
                              void* d_out, int out_size, void* d_ws, size_t ws_size,
                              hipStream_t stream) {
  const float* z    = (const float*)d_in[0];
  const float* tgt  = (const float*)d_in[1];
  const float* Wfh  = (const float*)d_in[2];
  const float* bfh  = (const float*)d_in[3];
  const float* Wfc  = (const float*)d_in[4];
  const float* bfc  = (const float*)d_in[5];
  const float* Wih0 = (const float*)d_in[6];
  const float* Whh0 = (const float*)d_in[7];
  const float* bih0 = (const float*)d_in[8];
  const float* bhh0 = (const float*)d_in[9];
  const float* Wih1 = (const float*)d_in[10];
  const float* Whh1 = (const float*)d_in[11];
  const float* bih1 = (const float*)d_in[12];
  const float* bhh1 = (const float*)d_in[13];
  const float* Wout = (const float*)d_in[14];
  const float* bout = (const float*)d_in[15];

  // ws layout (bytes), total ~7.93 MB
  char* ws = (char*)d_ws;
  unsigned short* p0  = (unsigned short*)(ws);                    // 589,824 B
  unsigned short* p1  = (unsigned short*)(ws + 589824);           // 1,048,576 B
  unsigned short* h0b = (unsigned short*)(ws + 1638400);          // 1,048,576 B
  unsigned short* h1b = (unsigned short*)(ws + 2686976);          // 1,048,576 B
  float*          c0s = (float*)(ws + 3735552);                   // 2,097,152 B
  float*          c1s = (float*)(ws + 5832704);                   // 2,097,152 B

  hipLaunchKernelGGL(init_state, dim3(BSZ * HDIM / 256), dim3(256), 0, stream,
                     z, Wfh, bfh, Wfc, bfc, h0b, c0s, h1b, c1s);
  hipLaunchKernelGGL(pack_weights, dim3(400), dim3(256), 0, stream,
                     Wih0, Whh0, Wih1, Whh1, p0, p1);
  hipLaunchKernelGGL(lstm_run, dim3(NWG), dim3(NTH), 0, stream,
                     tgt, p0, p1, bih0, bhh0, bih1, bhh1, Wout, bout,
                     h0b, h1b, c0s, c1s, (float*)d_out);
}